// Round 6
// baseline (564.403 us; speedup 1.0000x reference)
//
#include <hip/hip_runtime.h>
#include <math.h>

// Problem constants
constexpr int Bc = 4, Sc = 1024, Dc = 2048, HDc = 128, Hc = 16;
constexpr int BSc = Bc * Sc;        // 4096 token rows
constexpr int KQKc = Bc * HDc;      // 512 = batch-concat K dim for SS GEMM
#define GN_EPS 1e-3f

typedef __bf16 bf16x8 __attribute__((ext_vector_type(8)));
typedef __bf16 bf16x4 __attribute__((ext_vector_type(4)));
typedef float f32x4 __attribute__((ext_vector_type(4)));

// Workspace layout (float units)
constexpr size_t OFF_Q   = 0;                                  // bf16 [H][S][512]
constexpr size_t OFF_K   = OFF_Q + (size_t)Hc * Sc * KQKc / 2; // bf16 same
constexpr size_t OFF_VB  = OFF_K + (size_t)Hc * Sc * KQKc / 2; // bf16 [BS][D]
constexpr size_t OFF_VT  = OFF_VB + (size_t)BSc * Dc / 2;      // bf16 [BH][128][1024]
constexpr size_t OFF_A   = OFF_VT + (size_t)BSc * Dc / 2;      // bf16 [H][S][S]
constexpr size_t OFF_O   = OFF_A + (size_t)Hc * Sc * Sc / 2;   // fp32 [BS][D]
constexpr size_t OFF_CT  = OFF_O + (size_t)BSc * Dc;           // [H][S]
constexpr size_t OFF_PN  = OFF_CT + (size_t)Hc * Sc;           // [H][S]
constexpr size_t OFF_XB  = OFF_PN + (size_t)Hc * Sc;           // bf16 [BS][D]
constexpr size_t OFF_WGT = OFF_XB + (size_t)BSc * Dc / 2;      // bf16 [D][D] T
constexpr size_t OFF_WOT = OFF_WGT + (size_t)Dc * Dc / 2;      // bf16 [D][D] T
constexpr size_t OFF_SUF = OFF_WOT + (size_t)Dc * Dc / 2;      // fp32 [64][9][128]
constexpr size_t OFF_T   = OFF_SUF + (size_t)64 * 9 * HDc;     // fp32 [64][8][128]
// G (bf16 [BS][D]) reuses the Q buffer (dead after k_ssm)

#define GLOAD_LDS16(gp, lp)                                               \
  __builtin_amdgcn_global_load_lds(                                       \
      (const __attribute__((address_space(1))) void*)(gp),                \
      (__attribute__((address_space(3))) void*)(lp), 16, 0, 0)

// Chunk-major staging (conflict-free LDS):
//   LDS chunk ch holds rows [ch*16, ch*16+16) x 32 k as [kchunk(4)][row(16)][8].
//   Staging lane l fetches global (row = ch*16 + (l&15), k = k0 + (l>>4)*8);
//   builtin writes LDS at chunkbase + l*16B -> exactly the layout above.
//   Fragment read (row, kq): offset = ch*512 + kq*128 + (row&15)*8 elems;
//   64 lanes hit 64 distinct consecutive 16B chunks -> no bank conflicts.

// ---------------------------------------------------------------------------
// Decay tables: Dn[h,s,t] = ct[h,t] * pn[h,s]  (t<=s), computed in double.
__global__ __launch_bounds__(256) void k_tables(float* __restrict__ ct,
                                                float* __restrict__ pn) {
  int idx = blockIdx.x * 256 + threadIdx.x;   // 0 .. H*S-1
  int h = idx >> 10, t = idx & 1023;
  double gamma = 1.0 - exp2(-(double)(5 + h));
  double l2g = log2(gamma);
  double r = 1.0 / gamma;
  double rowsum = (exp2(-(double)(t + 1) * l2g) - 1.0) / (r - 1.0);
  ct[idx] = (float)(exp2((double)t * l2g) / sqrt(rowsum));
  pn[idx] = (float)exp2(-(double)t * l2g);
}

// ---------------------------------------------------------------------------
// fp32 -> bf16 cast, 8 elems/thread
__global__ __launch_bounds__(256) void k_cast8(const float* __restrict__ src,
                                               __bf16* __restrict__ dst) {
  size_t i = ((size_t)blockIdx.x * 256 + threadIdx.x) * 8;
  float4 a = *(const float4*)(src + i);
  float4 b = *(const float4*)(src + i + 4);
  bf16x8 o;
  o[0] = (__bf16)a.x; o[1] = (__bf16)a.y; o[2] = (__bf16)a.z; o[3] = (__bf16)a.w;
  o[4] = (__bf16)b.x; o[5] = (__bf16)b.y; o[6] = (__bf16)b.z; o[7] = (__bf16)b.w;
  *(bf16x8*)(dst + i) = o;
}

// ---------------------------------------------------------------------------
// Transpose-cast: dst[n][k] = (bf16) src[k][n], 2048x2048. 32x32 LDS tile.
__global__ __launch_bounds__(256) void k_castT(const float* __restrict__ src,
                                               __bf16* __restrict__ dst) {
  __shared__ float t[32][33];
  const int bx = blockIdx.x, by = blockIdx.y;
  const int tid = threadIdx.x;
  const int lx = tid & 31, ly = tid >> 5;   // 32 x 8
  #pragma unroll
  for (int r = 0; r < 32; r += 8)
    t[ly + r][lx] = src[(size_t)(by * 32 + ly + r) * Dc + bx * 32 + lx];
  __syncthreads();
  #pragma unroll
  for (int r = 0; r < 32; r += 8)
    dst[(size_t)(bx * 32 + ly + r) * Dc + by * 32 + lx] = (__bf16)t[lx][ly + r];
}

// ---------------------------------------------------------------------------
// Per-head projection: out = in_head @ Wh[h].  32x128 tile, K=128, fp32 math,
// bf16 output. isv=0: [H][S][B][HD] (Q/K, K-contig 512); isv=1: [BS][DIM] (V).
__global__ __launch_bounds__(256) void k_proj(const float* __restrict__ xin,
                                              const float* __restrict__ Whp,
                                              __bf16* __restrict__ outp, int isv) {
  __shared__ float Xs[32][17];
  __shared__ float Ws[16][128];
  const int tid = threadIdx.x;
  const int h = blockIdx.y;
  const int r0 = blockIdx.x * 32;
  const int tx = tid & 31, ty = tid >> 5;
  const int tc = tx * 4, tr = ty * 4;
  const float* wp = Whp + h * HDc * HDc;
  float acc[4][4] = {};
  for (int k0 = 0; k0 < HDc; k0 += 16) {
    #pragma unroll
    for (int i = tid; i < 32 * 16; i += 256) {
      int row = i >> 4, kk = i & 15;
      Xs[row][kk] = xin[(r0 + row) * Dc + h * HDc + k0 + kk];
    }
    #pragma unroll
    for (int i = tid; i < 16 * 128; i += 256) {
      int kk = i >> 7, e = i & 127;
      Ws[kk][e] = wp[(k0 + kk) * HDc + e];
    }
    __syncthreads();
    #pragma unroll
    for (int kk = 0; kk < 16; ++kk) {
      float a[4];
      #pragma unroll
      for (int i = 0; i < 4; ++i) a[i] = Xs[tr + i][kk];
      const float4 b4 = *(const float4*)&Ws[kk][tc];
      const float b[4] = {b4.x, b4.y, b4.z, b4.w};
      #pragma unroll
      for (int i = 0; i < 4; ++i)
        #pragma unroll
        for (int j = 0; j < 4; ++j)
          acc[i][j] = fmaf(a[i], b[j], acc[i][j]);
    }
    __syncthreads();
  }
  #pragma unroll
  for (int i = 0; i < 4; ++i) {
    const int r = r0 + tr + i;
    bf16x4 o;
    #pragma unroll
    for (int j = 0; j < 4; ++j) o[j] = (__bf16)acc[i][j];
    if (isv) {
      *(bf16x4*)&outp[(size_t)r * Dc + h * HDc + tc] = o;
    } else {
      int bb = r >> 10, s = r & 1023;
      *(bf16x4*)&outp[((size_t)(h * Sc + s) * Bc + bb) * HDc + tc] = o;
    }
  }
}

// ---------------------------------------------------------------------------
// Transpose-cast V: VB[b][t][h*128+e] -> Vt[(b*16+h)][e][t]  (bf16 -> bf16)
__global__ __launch_bounds__(256) void k_vt(const __bf16* __restrict__ VB,
                                            __bf16* __restrict__ Vt) {
  __shared__ float tl[32][33];
  const int bh = blockIdx.z, bb = bh >> 4, h = bh & 15;
  const int t0 = blockIdx.x * 32, e0 = blockIdx.y * 32;
  const int tid = threadIdx.x;
  const int lx = tid & 31, ly = tid >> 5;
  #pragma unroll
  for (int r = 0; r < 32; r += 8)
    tl[ly + r][lx] =
        (float)VB[(size_t)(bb * Sc + t0 + ly + r) * Dc + h * HDc + e0 + lx];
  __syncthreads();
  #pragma unroll
  for (int r = 0; r < 32; r += 8)
    Vt[((size_t)bh * HDc + e0 + ly + r) * Sc + t0 + lx] = (__bf16)tl[lx][ly + r];
}

// ---------------------------------------------------------------------------
// Stage 1: per-(bh, 128-tile) partial sums of V along t.
__global__ __launch_bounds__(256) void k_vsum(const __bf16* __restrict__ VB,
                                              float* __restrict__ T) {
  const int jj = blockIdx.x, bh = blockIdx.y;
  const int bb = bh >> 4, h = bh & 15;
  const int tid = threadIdx.x;
  const int tp = tid >> 7, e = tid & 127;
  const __bf16* base =
      VB + (size_t)(bb * Sc + jj * 128 + tp * 64) * Dc + h * HDc + e;
  float a0 = 0.f, a1 = 0.f, a2 = 0.f, a3 = 0.f;
  float a4 = 0.f, a5 = 0.f, a6 = 0.f, a7 = 0.f;
  for (int t = 0; t < 64; t += 8) {
    a0 += (float)base[(size_t)(t + 0) * Dc];
    a1 += (float)base[(size_t)(t + 1) * Dc];
    a2 += (float)base[(size_t)(t + 2) * Dc];
    a3 += (float)base[(size_t)(t + 3) * Dc];
    a4 += (float)base[(size_t)(t + 4) * Dc];
    a5 += (float)base[(size_t)(t + 5) * Dc];
    a6 += (float)base[(size_t)(t + 6) * Dc];
    a7 += (float)base[(size_t)(t + 7) * Dc];
  }
  const float s = ((a0 + a1) + (a2 + a3)) + ((a4 + a5) + (a6 + a7));
  __shared__ float red[2][128];
  red[tp][e] = s;
  __syncthreads();
  if (tp == 0)
    T[((size_t)bh * 8 + jj) * HDc + e] = red[0][e] + red[1][e];
}

// ---------------------------------------------------------------------------
// Stage 2: suffix-scan tiles -> SufV[bh][j][e] = sum_{t >= 128*j} V[b,t,h,e].
__global__ __launch_bounds__(128) void k_vscan(const float* __restrict__ T,
                                               float* __restrict__ SufV) {
  const int bh = blockIdx.x;
  const int e = threadIdx.x;
  float acc = 0.f;
  SufV[((size_t)bh * 9 + 8) * HDc + e] = 0.f;
  for (int jj = 7; jj >= 1; --jj) {
    acc += T[((size_t)bh * 8 + jj) * HDc + e];
    SufV[((size_t)bh * 9 + jj) * HDc + e] = acc;
  }
}

// ---------------------------------------------------------------------------
// SS via MFMA: per head, A[h][s][t] = clamp(|ct[t]*pn[s]*(Q·K^T)/sqrt(128)|,1)
// for t<=s (upper tiles skipped; never read). 128x128 tiles, K=512, 8 waves.
// Chunk-major conflict-free LDS.
__global__ __launch_bounds__(512) void k_ssm(const __bf16* __restrict__ Q,
                                             const __bf16* __restrict__ Kb,
                                             const float* __restrict__ ct,
                                             const float* __restrict__ pn,
                                             __bf16* __restrict__ A) {
  const int bx = blockIdx.x, by = blockIdx.y;
  if (bx > by) return;               // strictly-upper tile: skip entirely
  const int h = blockIdx.z;
  const int t0 = bx * 128, s0 = by * 128;
  const int tid = threadIdx.x;
  __bf16* Ah = A + (size_t)h * Sc * Sc;
  __shared__ __bf16 Qs[128 * 32];
  __shared__ __bf16 Ks[128 * 32];
  const int wave = tid >> 6, lane = tid & 63;
  const int wm = (wave >> 2) * 64, wn = (wave & 3) * 32;
  const int grow = wave * 16 + (lane & 15);   // staging: global row in tile
  const int gkb = (lane >> 4) * 8;            // staging: k-chunk offset
  const int rl = lane & 15, kq = lane >> 4;
  f32x4 acc[4][2] = {{}};
  const __bf16* qbase = Q + (size_t)(h * Sc + s0) * KQKc;
  const __bf16* kbase = Kb + (size_t)(h * Sc + t0) * KQKc;
  const int cha = (wm >> 4), chb = (wn >> 4);
  for (int k0 = 0; k0 < KQKc; k0 += 32) {
    GLOAD_LDS16(qbase + (size_t)grow * KQKc + k0 + gkb, Qs + wave * 512);
    GLOAD_LDS16(kbase + (size_t)grow * KQKc + k0 + gkb, Ks + wave * 512);
    __syncthreads();
    bf16x8 a[4], b[2];
    #pragma unroll
    for (int i = 0; i < 4; ++i)
      a[i] = *(const bf16x8*)&Qs[(cha + i) * 512 + kq * 128 + rl * 8];
    #pragma unroll
    for (int j = 0; j < 2; ++j)
      b[j] = *(const bf16x8*)&Ks[(chb + j) * 512 + kq * 128 + rl * 8];
    #pragma unroll
    for (int i = 0; i < 4; ++i)
      #pragma unroll
      for (int j = 0; j < 2; ++j)
        acc[i][j] = __builtin_amdgcn_mfma_f32_16x16x32_bf16(a[i], b[j],
                                                            acc[i][j], 0, 0, 0);
    __syncthreads();
  }
  const float rs = 0.088388347648318447f;  // 1/sqrt(128)
  #pragma unroll
  for (int i = 0; i < 4; ++i) {
    #pragma unroll
    for (int j = 0; j < 2; ++j) {
      const int t = t0 + wn + j * 16 + rl;
      const float ctv = ct[h * Sc + t] * rs;
      #pragma unroll
      for (int r = 0; r < 4; ++r) {
        const int s = s0 + wm + i * 16 + kq * 4 + r;
        float v = 1.0f;
        if (t <= s) v = fmaxf(fabsf(ctv * pn[h * Sc + s] * acc[i][j][r]), 1.0f);
        Ah[(size_t)s * Sc + t] = (__bf16)v;
      }
    }
  }
}

// ---------------------------------------------------------------------------
// O = A @ V via MFMA, triangular; all-ones region added as fp32 SufV.
// 8 waves, tile 128(s) x 128(e). Chunk-major conflict-free LDS.
__global__ __launch_bounds__(512) void k_avm(const __bf16* __restrict__ A,
                                             const __bf16* __restrict__ Vt,
                                             const float* __restrict__ SufV,
                                             float* __restrict__ O) {
  const int bh = blockIdx.z, bb = bh >> 4, h = bh & 15;
  const int itile = blockIdx.x;
  const int s0 = itile * 128;
  const int tid = threadIdx.x;
  __shared__ __bf16 As[128 * 32];
  __shared__ __bf16 Bs[128 * 32];
  const int wave = tid >> 6, lane = tid & 63;
  const int wm = (wave >> 2) * 64, wn = (wave & 3) * 32;
  const int grow = wave * 16 + (lane & 15);
  const int gkb = (lane >> 4) * 8;
  const int rl = lane & 15, kq = lane >> 4;
  f32x4 acc[4][2] = {{}};
  const __bf16* abase = A + (size_t)(h * Sc + s0) * Sc;
  const __bf16* vbase = Vt + (size_t)bh * HDc * Sc;
  const int cha = (wm >> 4), chb = (wn >> 4);
  const int kmax = (itile + 1) * 128;
  for (int k0 = 0; k0 < kmax; k0 += 32) {
    GLOAD_LDS16(abase + (size_t)grow * Sc + k0 + gkb, As + wave * 512);
    GLOAD_LDS16(vbase + (size_t)grow * Sc + k0 + gkb, Bs + wave * 512);
    __syncthreads();
    bf16x8 a[4], b[2];
    #pragma unroll
    for (int i = 0; i < 4; ++i)
      a[i] = *(const bf16x8*)&As[(cha + i) * 512 + kq * 128 + rl * 8];
    #pragma unroll
    for (int j = 0; j < 2; ++j)
      b[j] = *(const bf16x8*)&Bs[(chb + j) * 512 + kq * 128 + rl * 8];
    #pragma unroll
    for (int i = 0; i < 4; ++i)
      #pragma unroll
      for (int j = 0; j < 2; ++j)
        acc[i][j] = __builtin_amdgcn_mfma_f32_16x16x32_bf16(a[i], b[j],
                                                            acc[i][j], 0, 0, 0);
    __syncthreads();
  }
  const float* sufr = SufV + ((size_t)bh * 9 + (itile + 1)) * HDc;
  #pragma unroll
  for (int i = 0; i < 4; ++i) {
    #pragma unroll
    for (int j = 0; j < 2; ++j) {
      const int e = wn + j * 16 + rl;
      const float sv = sufr[e];
      #pragma unroll
      for (int r = 0; r < 4; ++r) {
        const int s = s0 + wm + i * 16 + kq * 4 + r;
        O[(size_t)(bb * Sc + s) * Dc + h * HDc + e] = acc[i][j][r] + sv;
      }
    }
  }
}

// ---------------------------------------------------------------------------
// Per-token GroupNorm(groups=1) over 2048 channels, in place.
__global__ __launch_bounds__(256) void k_gnorm(float* __restrict__ O,
                                               const float* __restrict__ gw,
                                               const float* __restrict__ bw) {
  const int r = blockIdx.x;
  const int tid = threadIdx.x;
  float* row = O + (size_t)r * Dc;
  const int c = tid * 4;
  float4 v0 = *(const float4*)(row + c);
  float4 v1 = *(const float4*)(row + c + 1024);
  __shared__ float red[256];
  __shared__ float sh_mu, sh_inv;
  red[tid] = v0.x + v0.y + v0.z + v0.w + v1.x + v1.y + v1.z + v1.w;
  __syncthreads();
  for (int st = 128; st > 0; st >>= 1) {
    if (tid < st) red[tid] += red[tid + st];
    __syncthreads();
  }
  if (tid == 0) sh_mu = red[0] * (1.0f / Dc);
  __syncthreads();
  const float mu = sh_mu;
  float d[8] = {v0.x - mu, v0.y - mu, v0.z - mu, v0.w - mu,
                v1.x - mu, v1.y - mu, v1.z - mu, v1.w - mu};
  float ssq = 0.f;
  #pragma unroll
  for (int i = 0; i < 8; ++i) ssq += d[i] * d[i];
  red[tid] = ssq;
  __syncthreads();
  for (int st = 128; st > 0; st >>= 1) {
    if (tid < st) red[tid] += red[tid + st];
    __syncthreads();
  }
  if (tid == 0) sh_inv = rsqrtf(red[0] * (1.0f / Dc) + GN_EPS);
  __syncthreads();
  const float inv = sh_inv;
  float4 g0 = *(const float4*)(gw + c), g1 = *(const float4*)(gw + c + 1024);
  float4 b0 = *(const float4*)(bw + c), b1 = *(const float4*)(bw + c + 1024);
  float4 o0, o1;
  o0.x = d[0] * inv * g0.x + b0.x; o0.y = d[1] * inv * g0.y + b0.y;
  o0.z = d[2] * inv * g0.z + b0.z; o0.w = d[3] * inv * g0.w + b0.w;
  o1.x = d[4] * inv * g1.x + b1.x; o1.y = d[5] * inv * g1.y + b1.y;
  o1.z = d[6] * inv * g1.z + b1.z; o1.w = d[7] * inv * g1.w + b1.w;
  *(float4*)(row + c) = o0;
  *(float4*)(row + c + 1024) = o1;
}

// ---------------------------------------------------------------------------
// bf16 MFMA GEMM: C = A @ Bt^T. M=4096, N=2048, K=2048. 8 waves, tile 128x128,
// wave tile 64x32. Chunk-major conflict-free LDS.
// mode 0: Gout = bf16(relu(acc) * Y);  mode 1: Fout = acc (fp32).
__global__ __launch_bounds__(512) void k_mgemm(const __bf16* __restrict__ Ab,
                                               const __bf16* __restrict__ Bt,
                                               const float* __restrict__ Y,
                                               __bf16* __restrict__ Gout,
                                               float* __restrict__ Fout,
                                               int mode) {
  __shared__ __bf16 As[128 * 32];
  __shared__ __bf16 Bs[128 * 32];
  const int tid = threadIdx.x;
  const int wave = tid >> 6, lane = tid & 63;
  const int r0 = blockIdx.y * 128, c0 = blockIdx.x * 128;
  const int wm = (wave >> 2) * 64, wn = (wave & 3) * 32;
  const int grow = wave * 16 + (lane & 15);
  const int gkb = (lane >> 4) * 8;
  const int rl = lane & 15, kq = lane >> 4;
  const int cha = (wm >> 4), chb = (wn >> 4);
  f32x4 acc[4][2] = {{}};

  for (int k0 = 0; k0 < Dc; k0 += 32) {
    GLOAD_LDS16(Ab + (size_t)(r0 + grow) * Dc + k0 + gkb, As + wave * 512);
    GLOAD_LDS16(Bt + (size_t)(c0 + grow) * Dc + k0 + gkb, Bs + wave * 512);
    __syncthreads();
    bf16x8 a[4], b[2];
    #pragma unroll
    for (int i = 0; i < 4; ++i)
      a[i] = *(const bf16x8*)&As[(cha + i) * 512 + kq * 128 + rl * 8];
    #pragma unroll
    for (int j = 0; j < 2; ++j)
      b[j] = *(const bf16x8*)&Bs[(chb + j) * 512 + kq * 128 + rl * 8];
    #pragma unroll
    for (int i = 0; i < 4; ++i)
      #pragma unroll
      for (int j = 0; j < 2; ++j)
        acc[i][j] = __builtin_amdgcn_mfma_f32_16x16x32_bf16(a[i], b[j],
                                                            acc[i][j], 0, 0, 0);
    __syncthreads();
  }

  #pragma unroll
  for (int i = 0; i < 4; ++i) {
    #pragma unroll
    for (int j = 0; j < 2; ++j) {
      const int col = c0 + wn + j * 16 + rl;
      #pragma unroll
      for (int r = 0; r < 4; ++r) {
        const int row = r0 + wm + i * 16 + kq * 4 + r;
        const size_t idx = (size_t)row * Dc + col;
        float v = acc[i][j][r];
        if (mode == 0) {
          v = fmaxf(v, 0.f) * Y[idx];
          Gout[idx] = (__bf16)v;
        } else {
          Fout[idx] = v;
        }
      }
    }
  }
}

// ---------------------------------------------------------------------------
extern "C" void kernel_launch(void* const* d_in, const int* in_sizes, int n_in,
                              void* d_out, int out_size, void* d_ws, size_t ws_size,
                              hipStream_t stream) {
  const float* x  = (const float*)d_in[0];
  const float* k  = (const float*)d_in[1];
  const float* v  = (const float*)d_in[2];
  const float* Wh = (const float*)d_in[3];
  const float* wg = (const float*)d_in[4];
  const float* wo = (const float*)d_in[5];
  const float* gg = (const float*)d_in[6];
  const float* gb = (const float*)d_in[7];
  float* ws = (float*)d_ws;
  __bf16* Q   = (__bf16*)(ws + OFF_Q);
  __bf16* Kp  = (__bf16*)(ws + OFF_K);
  __bf16* VB  = (__bf16*)(ws + OFF_VB);
  __bf16* Vt  = (__bf16*)(ws + OFF_VT);
  __bf16* A   = (__bf16*)(ws + OFF_A);
  float*  O   = ws + OFF_O;
  float*  CT  = ws + OFF_CT;
  float*  PN  = ws + OFF_PN;
  __bf16* XB  = (__bf16*)(ws + OFF_XB);
  __bf16* WGT = (__bf16*)(ws + OFF_WGT);
  __bf16* WOT = (__bf16*)(ws + OFF_WOT);
  float*  SUF = ws + OFF_SUF;
  float*  TP  = ws + OFF_T;
  __bf16* G   = (__bf16*)(ws + OFF_Q);  // reuse Q region (dead after k_ssm)

  k_tables<<<Hc * Sc / 256, 256, 0, stream>>>(CT, PN);
  k_cast8<<<(BSc * Dc) / (256 * 8), 256, 0, stream>>>(x, XB);
  k_castT<<<dim3(Dc / 32, Dc / 32), 256, 0, stream>>>(wg, WGT);
  k_castT<<<dim3(Dc / 32, Dc / 32), 256, 0, stream>>>(wo, WOT);
  k_proj<<<dim3(BSc / 32, Hc), 256, 0, stream>>>(x, Wh, Q, 0);
  k_proj<<<dim3(BSc / 32, Hc), 256, 0, stream>>>(k, Wh, Kp, 0);
  k_proj<<<dim3(BSc / 32, Hc), 256, 0, stream>>>(v, Wh, VB, 1);
  k_vt<<<dim3(Sc / 32, HDc / 32, Bc * Hc), 256, 0, stream>>>(VB, Vt);
  k_vsum<<<dim3(8, Bc * Hc), 256, 0, stream>>>(VB, TP);
  k_vscan<<<Bc * Hc, 128, 0, stream>>>(TP, SUF);
  k_ssm<<<dim3(Sc / 128, Sc / 128, Hc), 512, 0, stream>>>(Q, Kp, CT, PN, A);
  k_avm<<<dim3(Sc / 128, 1, Bc * Hc), 512, 0, stream>>>(A, Vt, SUF, O);
  k_gnorm<<<BSc, 256, 0, stream>>>(O, gg, gb);
  k_mgemm<<<dim3(Dc / 128, BSc / 128), 512, 0, stream>>>(XB, WGT, O, G, nullptr, 0);
  k_mgemm<<<dim3(Dc / 128, BSc / 128), 512, 0, stream>>>(G, WOT, nullptr, nullptr,
                                                         (float*)d_out, 1);
}

// Round 7
// 399.395 us; speedup vs baseline: 1.4131x; 1.4131x over previous
//
#include <hip/hip_runtime.h>
#include <math.h>

// Problem constants
constexpr int Bc = 4, Sc = 1024, Dc = 2048, HDc = 128, Hc = 16;
constexpr int BSc = Bc * Sc;        // 4096 token rows
constexpr int KQKc = Bc * HDc;      // 512 = batch-concat K dim for SS GEMM
#define GN_EPS 1e-3f

typedef __bf16 bf16x8 __attribute__((ext_vector_type(8)));
typedef __bf16 bf16x4 __attribute__((ext_vector_type(4)));
typedef float f32x4 __attribute__((ext_vector_type(4)));

// Workspace layout (float units)
constexpr size_t OFF_Q   = 0;                                  // bf16 [H][S][512]
constexpr size_t OFF_K   = OFF_Q + (size_t)Hc * Sc * KQKc / 2; // bf16 same
constexpr size_t OFF_VB  = OFF_K + (size_t)Hc * Sc * KQKc / 2; // bf16 [BS][D]
constexpr size_t OFF_VT  = OFF_VB + (size_t)BSc * Dc / 2;      // bf16 [BH][128][1024]
constexpr size_t OFF_A   = OFF_VT + (size_t)BSc * Dc / 2;      // bf16 [H][S][S]
constexpr size_t OFF_O   = OFF_A + (size_t)Hc * Sc * Sc / 2;   // fp32 [BS][D]
constexpr size_t OFF_CT  = OFF_O + (size_t)BSc * Dc;           // [H][S]
constexpr size_t OFF_PN  = OFF_CT + (size_t)Hc * Sc;           // [H][S]
constexpr size_t OFF_XB  = OFF_PN + (size_t)Hc * Sc;           // bf16 [BS][D]
constexpr size_t OFF_WGT = OFF_XB + (size_t)BSc * Dc / 2;      // bf16 [D][D] T
constexpr size_t OFF_WOT = OFF_WGT + (size_t)Dc * Dc / 2;      // bf16 [D][D] T
constexpr size_t OFF_SUF = OFF_WOT + (size_t)Dc * Dc / 2;      // fp32 [64][9][128]
constexpr size_t OFF_T   = OFF_SUF + (size_t)64 * 9 * HDc;     // fp32 [64][8][128]
constexpr size_t OFF_WHT = OFF_T + (size_t)64 * 8 * HDc;       // bf16 [H][128][128]
// KB2 / VB2 (bf16 casts of raw k, v) alias the A region (dead until k_ssm).
// G (bf16 [BS][D]) reuses the Q buffer (dead after k_ssm).
constexpr size_t OFF_KB2 = OFF_A;
constexpr size_t OFF_VB2 = OFF_A + (size_t)BSc * Dc / 2;

#define GLOAD_LDS16(gp, lp)                                               \
  __builtin_amdgcn_global_load_lds(                                       \
      (const __attribute__((address_space(1))) void*)(gp),                \
      (__attribute__((address_space(3))) void*)(lp), 16, 0, 0)

// Swizzled staging: lane l stages row l>>2 (4 lanes/row -> one 64B segment,
// coalesced) at k-chunk c = (l&3) ^ key(row), key(r) = (r>>1)&3. LDS layout:
// (r,c) at chunkbase + r*32 + (c^key(r))*8 elems. Fragment read (rl,kq) ->
// 16B unit rl*4 + (kq^key(rl)): all 64 distinct, 8-lane groups hit 8 distinct
// bank quads -> conflict-free ds_read_b128 AND coalesced global fetch.

// ---------------------------------------------------------------------------
// Decay tables: Dn[h,s,t] = ct[h,t] * pn[h,s]  (t<=s), computed in double.
__global__ __launch_bounds__(256) void k_tables(float* __restrict__ ct,
                                                float* __restrict__ pn) {
  int idx = blockIdx.x * 256 + threadIdx.x;   // 0 .. H*S-1
  int h = idx >> 10, t = idx & 1023;
  double gamma = 1.0 - exp2(-(double)(5 + h));
  double l2g = log2(gamma);
  double r = 1.0 / gamma;
  double rowsum = (exp2(-(double)(t + 1) * l2g) - 1.0) / (r - 1.0);
  ct[idx] = (float)(exp2((double)t * l2g) / sqrt(rowsum));
  pn[idx] = (float)exp2(-(double)t * l2g);
}

// ---------------------------------------------------------------------------
// fp32 -> bf16 cast, 8 elems/thread
__global__ __launch_bounds__(256) void k_cast8(const float* __restrict__ src,
                                               __bf16* __restrict__ dst) {
  size_t i = ((size_t)blockIdx.x * 256 + threadIdx.x) * 8;
  float4 a = *(const float4*)(src + i);
  float4 b = *(const float4*)(src + i + 4);
  bf16x8 o;
  o[0] = (__bf16)a.x; o[1] = (__bf16)a.y; o[2] = (__bf16)a.z; o[3] = (__bf16)a.w;
  o[4] = (__bf16)b.x; o[5] = (__bf16)b.y; o[6] = (__bf16)b.z; o[7] = (__bf16)b.w;
  *(bf16x8*)(dst + i) = o;
}

// ---------------------------------------------------------------------------
// Transpose-cast: dst[n][k] = (bf16) src[k][n], 2048x2048. 32x32 LDS tile.
__global__ __launch_bounds__(256) void k_castT(const float* __restrict__ src,
                                               __bf16* __restrict__ dst) {
  __shared__ float t[32][33];
  const int bx = blockIdx.x, by = blockIdx.y;
  const int tid = threadIdx.x;
  const int lx = tid & 31, ly = tid >> 5;   // 32 x 8
  #pragma unroll
  for (int r = 0; r < 32; r += 8)
    t[ly + r][lx] = src[(size_t)(by * 32 + ly + r) * Dc + bx * 32 + lx];
  __syncthreads();
  #pragma unroll
  for (int r = 0; r < 32; r += 8)
    dst[(size_t)(bx * 32 + ly + r) * Dc + by * 32 + lx] = (__bf16)t[lx][ly + r];
}

// ---------------------------------------------------------------------------
// Per-head transpose-cast of Wh: WhT[h][e][d] = (bf16) Wh[h][d][e].
__global__ __launch_bounds__(256) void k_whT(const float* __restrict__ Wh,
                                             __bf16* __restrict__ WhT) {
  __shared__ float t[32][33];
  const int h = blockIdx.z;
  const int d0 = blockIdx.x * 32, e0 = blockIdx.y * 32;
  const int tid = threadIdx.x;
  const int lx = tid & 31, ly = tid >> 5;
  #pragma unroll
  for (int r = 0; r < 32; r += 8)
    t[ly + r][lx] = Wh[(size_t)h * HDc * HDc + (d0 + ly + r) * HDc + e0 + lx];
  __syncthreads();
  #pragma unroll
  for (int r = 0; r < 32; r += 8)
    WhT[(size_t)h * HDc * HDc + (e0 + ly + r) * HDc + d0 + lx] =
        (__bf16)t[lx][ly + r];
}

// ---------------------------------------------------------------------------
// MFMA projections: per head, C = Xin[:, h-slice] @ WhT[h]^T (K=128).
// z=0: Xb -> Q layout [h][s][b*HD]; z=1: Kb2 -> K layout; z=2: Vb2 -> Vp [BS][D].
// 8 waves, tile 128x128, wave tile 64x32, BK=32 (4 iters). Swizzled staging.
__global__ __launch_bounds__(512) void k_projm(const __bf16* __restrict__ Xb,
                                               const __bf16* __restrict__ Kb2,
                                               const __bf16* __restrict__ Vb2,
                                               const __bf16* __restrict__ WhT,
                                               __bf16* __restrict__ Qo,
                                               __bf16* __restrict__ Ko,
                                               __bf16* __restrict__ Vo) {
  const int r0 = blockIdx.x * 128;
  const int h = blockIdx.y;
  const int z = blockIdx.z;
  const __bf16* src = (z == 0) ? Xb : (z == 1) ? Kb2 : Vb2;
  __shared__ __bf16 As[128 * 32];
  __shared__ __bf16 Bs[128 * 32];
  const int tid = threadIdx.x;
  const int wave = tid >> 6, lane = tid & 63;
  const int wm = (wave >> 2) * 64, wn = (wave & 3) * 32;
  const int grow = wave * 16 + (lane >> 2);
  const int gkb = ((lane & 3) ^ ((lane >> 3) & 3)) * 8;
  const int rl = lane & 15, kq = lane >> 4;
  const int sw8 = (kq ^ ((rl >> 1) & 3)) * 8;
  const int cha = wm >> 4, chb = wn >> 4;
  const __bf16* wb = WhT + (size_t)h * HDc * HDc;
  f32x4 acc[4][2] = {{}};
  for (int k0 = 0; k0 < HDc; k0 += 32) {
    GLOAD_LDS16(src + (size_t)(r0 + grow) * Dc + h * HDc + k0 + gkb,
                As + wave * 512);
    GLOAD_LDS16(wb + (size_t)grow * HDc + k0 + gkb, Bs + wave * 512);
    __syncthreads();
    bf16x8 a[4], b[2];
    #pragma unroll
    for (int i = 0; i < 4; ++i)
      a[i] = *(const bf16x8*)&As[(cha + i) * 512 + rl * 32 + sw8];
    #pragma unroll
    for (int j = 0; j < 2; ++j)
      b[j] = *(const bf16x8*)&Bs[(chb + j) * 512 + rl * 32 + sw8];
    #pragma unroll
    for (int i = 0; i < 4; ++i)
      #pragma unroll
      for (int j = 0; j < 2; ++j)
        acc[i][j] = __builtin_amdgcn_mfma_f32_16x16x32_bf16(a[i], b[j],
                                                            acc[i][j], 0, 0, 0);
    __syncthreads();
  }
  #pragma unroll
  for (int i = 0; i < 4; ++i) {
    #pragma unroll
    for (int j = 0; j < 2; ++j) {
      const int col = wn + j * 16 + rl;
      #pragma unroll
      for (int r = 0; r < 4; ++r) {
        const int row = r0 + wm + i * 16 + kq * 4 + r;
        const __bf16 v = (__bf16)acc[i][j][r];
        if (z == 2) {
          Vo[(size_t)row * Dc + h * HDc + col] = v;
        } else {
          const int s = row & 1023, bb = row >> 10;
          __bf16* dst = (z == 0) ? Qo : Ko;
          dst[((size_t)(h * Sc + s) * Bc + bb) * HDc + col] = v;
        }
      }
    }
  }
}

// ---------------------------------------------------------------------------
// Transpose-cast V: VB[b][t][h*128+e] -> Vt[(b*16+h)][e][t]  (bf16 -> bf16)
__global__ __launch_bounds__(256) void k_vt(const __bf16* __restrict__ VB,
                                            __bf16* __restrict__ Vt) {
  __shared__ float tl[32][33];
  const int bh = blockIdx.z, bb = bh >> 4, h = bh & 15;
  const int t0 = blockIdx.x * 32, e0 = blockIdx.y * 32;
  const int tid = threadIdx.x;
  const int lx = tid & 31, ly = tid >> 5;
  #pragma unroll
  for (int r = 0; r < 32; r += 8)
    tl[ly + r][lx] =
        (float)VB[(size_t)(bb * Sc + t0 + ly + r) * Dc + h * HDc + e0 + lx];
  __syncthreads();
  #pragma unroll
  for (int r = 0; r < 32; r += 8)
    Vt[((size_t)bh * HDc + e0 + ly + r) * Sc + t0 + lx] = (__bf16)tl[lx][ly + r];
}

// ---------------------------------------------------------------------------
// Stage 1: per-(bh, 128-tile) partial sums of V along t.
__global__ __launch_bounds__(256) void k_vsum(const __bf16* __restrict__ VB,
                                              float* __restrict__ T) {
  const int jj = blockIdx.x, bh = blockIdx.y;
  const int bb = bh >> 4, h = bh & 15;
  const int tid = threadIdx.x;
  const int tp = tid >> 7, e = tid & 127;
  const __bf16* base =
      VB + (size_t)(bb * Sc + jj * 128 + tp * 64) * Dc + h * HDc + e;
  float a0 = 0.f, a1 = 0.f, a2 = 0.f, a3 = 0.f;
  float a4 = 0.f, a5 = 0.f, a6 = 0.f, a7 = 0.f;
  for (int t = 0; t < 64; t += 8) {
    a0 += (float)base[(size_t)(t + 0) * Dc];
    a1 += (float)base[(size_t)(t + 1) * Dc];
    a2 += (float)base[(size_t)(t + 2) * Dc];
    a3 += (float)base[(size_t)(t + 3) * Dc];
    a4 += (float)base[(size_t)(t + 4) * Dc];
    a5 += (float)base[(size_t)(t + 5) * Dc];
    a6 += (float)base[(size_t)(t + 6) * Dc];
    a7 += (float)base[(size_t)(t + 7) * Dc];
  }
  const float s = ((a0 + a1) + (a2 + a3)) + ((a4 + a5) + (a6 + a7));
  __shared__ float red[2][128];
  red[tp][e] = s;
  __syncthreads();
  if (tp == 0)
    T[((size_t)bh * 8 + jj) * HDc + e] = red[0][e] + red[1][e];
}

// ---------------------------------------------------------------------------
// Stage 2: suffix-scan tiles -> SufV[bh][j][e] = sum_{t >= 128*j} V[b,t,h,e].
__global__ __launch_bounds__(128) void k_vscan(const float* __restrict__ T,
                                               float* __restrict__ SufV) {
  const int bh = blockIdx.x;
  const int e = threadIdx.x;
  float acc = 0.f;
  SufV[((size_t)bh * 9 + 8) * HDc + e] = 0.f;
  for (int jj = 7; jj >= 1; --jj) {
    acc += T[((size_t)bh * 8 + jj) * HDc + e];
    SufV[((size_t)bh * 9 + jj) * HDc + e] = acc;
  }
}

// ---------------------------------------------------------------------------
// SS via MFMA: per head, A[h][s][t] = clamp(|ct[t]*pn[s]*(Q·K^T)/sqrt(128)|,1)
// for t<=s (upper tiles skipped; never read). 128x128 tiles, K=512, 8 waves.
// Swizzled conflict-free + coalesced staging.
__global__ __launch_bounds__(512) void k_ssm(const __bf16* __restrict__ Q,
                                             const __bf16* __restrict__ Kb,
                                             const float* __restrict__ ct,
                                             const float* __restrict__ pn,
                                             __bf16* __restrict__ A) {
  const int bx = blockIdx.x, by = blockIdx.y;
  if (bx > by) return;               // strictly-upper tile: skip entirely
  const int h = blockIdx.z;
  const int t0 = bx * 128, s0 = by * 128;
  const int tid = threadIdx.x;
  __bf16* Ah = A + (size_t)h * Sc * Sc;
  __shared__ __bf16 Qs[128 * 32];
  __shared__ __bf16 Ks[128 * 32];
  const int wave = tid >> 6, lane = tid & 63;
  const int wm = (wave >> 2) * 64, wn = (wave & 3) * 32;
  const int grow = wave * 16 + (lane >> 2);
  const int gkb = ((lane & 3) ^ ((lane >> 3) & 3)) * 8;
  const int rl = lane & 15, kq = lane >> 4;
  const int sw8 = (kq ^ ((rl >> 1) & 3)) * 8;
  const int cha = wm >> 4, chb = wn >> 4;
  f32x4 acc[4][2] = {{}};
  const __bf16* qbase = Q + (size_t)(h * Sc + s0) * KQKc;
  const __bf16* kbase = Kb + (size_t)(h * Sc + t0) * KQKc;
  for (int k0 = 0; k0 < KQKc; k0 += 32) {
    GLOAD_LDS16(qbase + (size_t)grow * KQKc + k0 + gkb, Qs + wave * 512);
    GLOAD_LDS16(kbase + (size_t)grow * KQKc + k0 + gkb, Ks + wave * 512);
    __syncthreads();
    bf16x8 a[4], b[2];
    #pragma unroll
    for (int i = 0; i < 4; ++i)
      a[i] = *(const bf16x8*)&Qs[(cha + i) * 512 + rl * 32 + sw8];
    #pragma unroll
    for (int j = 0; j < 2; ++j)
      b[j] = *(const bf16x8*)&Ks[(chb + j) * 512 + rl * 32 + sw8];
    #pragma unroll
    for (int i = 0; i < 4; ++i)
      #pragma unroll
      for (int j = 0; j < 2; ++j)
        acc[i][j] = __builtin_amdgcn_mfma_f32_16x16x32_bf16(a[i], b[j],
                                                            acc[i][j], 0, 0, 0);
    __syncthreads();
  }
  const float rs = 0.088388347648318447f;  // 1/sqrt(128)
  #pragma unroll
  for (int i = 0; i < 4; ++i) {
    #pragma unroll
    for (int j = 0; j < 2; ++j) {
      const int t = t0 + wn + j * 16 + rl;
      const float ctv = ct[h * Sc + t] * rs;
      #pragma unroll
      for (int r = 0; r < 4; ++r) {
        const int s = s0 + wm + i * 16 + kq * 4 + r;
        float v = 1.0f;
        if (t <= s) v = fmaxf(fabsf(ctv * pn[h * Sc + s] * acc[i][j][r]), 1.0f);
        Ah[(size_t)s * Sc + t] = (__bf16)v;
      }
    }
  }
}

// ---------------------------------------------------------------------------
// O = A @ V via MFMA, triangular; all-ones region added as fp32 SufV.
// 8 waves, tile 128(s) x 128(e). Swizzled staging.
__global__ __launch_bounds__(512) void k_avm(const __bf16* __restrict__ A,
                                             const __bf16* __restrict__ Vt,
                                             const float* __restrict__ SufV,
                                             float* __restrict__ O) {
  const int bh = blockIdx.z, bb = bh >> 4, h = bh & 15;
  const int itile = blockIdx.x;
  const int s0 = itile * 128;
  const int tid = threadIdx.x;
  __shared__ __bf16 As[128 * 32];
  __shared__ __bf16 Bs[128 * 32];
  const int wave = tid >> 6, lane = tid & 63;
  const int wm = (wave >> 2) * 64, wn = (wave & 3) * 32;
  const int grow = wave * 16 + (lane >> 2);
  const int gkb = ((lane & 3) ^ ((lane >> 3) & 3)) * 8;
  const int rl = lane & 15, kq = lane >> 4;
  const int sw8 = (kq ^ ((rl >> 1) & 3)) * 8;
  const int cha = wm >> 4, chb = wn >> 4;
  f32x4 acc[4][2] = {{}};
  const __bf16* abase = A + (size_t)(h * Sc + s0) * Sc;
  const __bf16* vbase = Vt + (size_t)bh * HDc * Sc;
  const int kmax = (itile + 1) * 128;
  for (int k0 = 0; k0 < kmax; k0 += 32) {
    GLOAD_LDS16(abase + (size_t)grow * Sc + k0 + gkb, As + wave * 512);
    GLOAD_LDS16(vbase + (size_t)grow * Sc + k0 + gkb, Bs + wave * 512);
    __syncthreads();
    bf16x8 a[4], b[2];
    #pragma unroll
    for (int i = 0; i < 4; ++i)
      a[i] = *(const bf16x8*)&As[(cha + i) * 512 + rl * 32 + sw8];
    #pragma unroll
    for (int j = 0; j < 2; ++j)
      b[j] = *(const bf16x8*)&Bs[(chb + j) * 512 + rl * 32 + sw8];
    #pragma unroll
    for (int i = 0; i < 4; ++i)
      #pragma unroll
      for (int j = 0; j < 2; ++j)
        acc[i][j] = __builtin_amdgcn_mfma_f32_16x16x32_bf16(a[i], b[j],
                                                            acc[i][j], 0, 0, 0);
    __syncthreads();
  }
  const float* sufr = SufV + ((size_t)bh * 9 + (itile + 1)) * HDc;
  #pragma unroll
  for (int i = 0; i < 4; ++i) {
    #pragma unroll
    for (int j = 0; j < 2; ++j) {
      const int e = wn + j * 16 + rl;
      const float sv = sufr[e];
      #pragma unroll
      for (int r = 0; r < 4; ++r) {
        const int s = s0 + wm + i * 16 + kq * 4 + r;
        O[(size_t)(bb * Sc + s) * Dc + h * HDc + e] = acc[i][j][r] + sv;
      }
    }
  }
}

// ---------------------------------------------------------------------------
// Per-token GroupNorm(groups=1) over 2048 channels, in place.
__global__ __launch_bounds__(256) void k_gnorm(float* __restrict__ O,
                                               const float* __restrict__ gw,
                                               const float* __restrict__ bw) {
  const int r = blockIdx.x;
  const int tid = threadIdx.x;
  float* row = O + (size_t)r * Dc;
  const int c = tid * 4;
  float4 v0 = *(const float4*)(row + c);
  float4 v1 = *(const float4*)(row + c + 1024);
  __shared__ float red[256];
  __shared__ float sh_mu, sh_inv;
  red[tid] = v0.x + v0.y + v0.z + v0.w + v1.x + v1.y + v1.z + v1.w;
  __syncthreads();
  for (int st = 128; st > 0; st >>= 1) {
    if (tid < st) red[tid] += red[tid + st];
    __syncthreads();
  }
  if (tid == 0) sh_mu = red[0] * (1.0f / Dc);
  __syncthreads();
  const float mu = sh_mu;
  float d[8] = {v0.x - mu, v0.y - mu, v0.z - mu, v0.w - mu,
                v1.x - mu, v1.y - mu, v1.z - mu, v1.w - mu};
  float ssq = 0.f;
  #pragma unroll
  for (int i = 0; i < 8; ++i) ssq += d[i] * d[i];
  red[tid] = ssq;
  __syncthreads();
  for (int st = 128; st > 0; st >>= 1) {
    if (tid < st) red[tid] += red[tid + st];
    __syncthreads();
  }
  if (tid == 0) sh_inv = rsqrtf(red[0] * (1.0f / Dc) + GN_EPS);
  __syncthreads();
  const float inv = sh_inv;
  float4 g0 = *(const float4*)(gw + c), g1 = *(const float4*)(gw + c + 1024);
  float4 b0 = *(const float4*)(bw + c), b1 = *(const float4*)(bw + c + 1024);
  float4 o0, o1;
  o0.x = d[0] * inv * g0.x + b0.x; o0.y = d[1] * inv * g0.y + b0.y;
  o0.z = d[2] * inv * g0.z + b0.z; o0.w = d[3] * inv * g0.w + b0.w;
  o1.x = d[4] * inv * g1.x + b1.x; o1.y = d[5] * inv * g1.y + b1.y;
  o1.z = d[6] * inv * g1.z + b1.z; o1.w = d[7] * inv * g1.w + b1.w;
  *(float4*)(row + c) = o0;
  *(float4*)(row + c + 1024) = o1;
}

// ---------------------------------------------------------------------------
// bf16 MFMA GEMM: C = A @ Bt^T. M=4096, N=2048, K=2048. 8 waves, tile 128x128,
// wave tile 64x32. Swizzled conflict-free + coalesced staging.
// mode 0: Gout = bf16(relu(acc) * Y);  mode 1: Fout = acc (fp32).
__global__ __launch_bounds__(512) void k_mgemm(const __bf16* __restrict__ Ab,
                                               const __bf16* __restrict__ Bt,
                                               const float* __restrict__ Y,
                                               __bf16* __restrict__ Gout,
                                               float* __restrict__ Fout,
                                               int mode) {
  __shared__ __bf16 As[128 * 32];
  __shared__ __bf16 Bs[128 * 32];
  const int tid = threadIdx.x;
  const int wave = tid >> 6, lane = tid & 63;
  const int r0 = blockIdx.y * 128, c0 = blockIdx.x * 128;
  const int wm = (wave >> 2) * 64, wn = (wave & 3) * 32;
  const int grow = wave * 16 + (lane >> 2);
  const int gkb = ((lane & 3) ^ ((lane >> 3) & 3)) * 8;
  const int rl = lane & 15, kq = lane >> 4;
  const int sw8 = (kq ^ ((rl >> 1) & 3)) * 8;
  const int cha = wm >> 4, chb = wn >> 4;
  f32x4 acc[4][2] = {{}};

  for (int k0 = 0; k0 < Dc; k0 += 32) {
    GLOAD_LDS16(Ab + (size_t)(r0 + grow) * Dc + k0 + gkb, As + wave * 512);
    GLOAD_LDS16(Bt + (size_t)(c0 + grow) * Dc + k0 + gkb, Bs + wave * 512);
    __syncthreads();
    bf16x8 a[4], b[2];
    #pragma unroll
    for (int i = 0; i < 4; ++i)
      a[i] = *(const bf16x8*)&As[(cha + i) * 512 + rl * 32 + sw8];
    #pragma unroll
    for (int j = 0; j < 2; ++j)
      b[j] = *(const bf16x8*)&Bs[(chb + j) * 512 + rl * 32 + sw8];
    #pragma unroll
    for (int i = 0; i < 4; ++i)
      #pragma unroll
      for (int j = 0; j < 2; ++j)
        acc[i][j] = __builtin_amdgcn_mfma_f32_16x16x32_bf16(a[i], b[j],
                                                            acc[i][j], 0, 0, 0);
    __syncthreads();
  }

  #pragma unroll
  for (int i = 0; i < 4; ++i) {
    #pragma unroll
    for (int j = 0; j < 2; ++j) {
      const int col = c0 + wn + j * 16 + rl;
      #pragma unroll
      for (int r = 0; r < 4; ++r) {
        const int row = r0 + wm + i * 16 + kq * 4 + r;
        const size_t idx = (size_t)row * Dc + col;
        float v = acc[i][j][r];
        if (mode == 0) {
          v = fmaxf(v, 0.f) * Y[idx];
          Gout[idx] = (__bf16)v;
        } else {
          Fout[idx] = v;
        }
      }
    }
  }
}

// ---------------------------------------------------------------------------
extern "C" void kernel_launch(void* const* d_in, const int* in_sizes, int n_in,
                              void* d_out, int out_size, void* d_ws, size_t ws_size,
                              hipStream_t stream) {
  const float* x  = (const float*)d_in[0];
  const float* k  = (const float*)d_in[1];
  const float* v  = (const float*)d_in[2];
  const float* Wh = (const float*)d_in[3];
  const float* wg = (const float*)d_in[4];
  const float* wo = (const float*)d_in[5];
  const float* gg = (const float*)d_in[6];
  const float* gb = (const float*)d_in[7];
  float* ws = (float*)d_ws;
  __bf16* Q   = (__bf16*)(ws + OFF_Q);
  __bf16* Kp  = (__bf16*)(ws + OFF_K);
  __bf16* VB  = (__bf16*)(ws + OFF_VB);
  __bf16* Vt  = (__bf16*)(ws + OFF_VT);
  __bf16* A   = (__bf16*)(ws + OFF_A);
  float*  O   = ws + OFF_O;
  float*  CT  = ws + OFF_CT;
  float*  PN  = ws + OFF_PN;
  __bf16* XB  = (__bf16*)(ws + OFF_XB);
  __bf16* WGT = (__bf16*)(ws + OFF_WGT);
  __bf16* WOT = (__bf16*)(ws + OFF_WOT);
  float*  SUF = ws + OFF_SUF;
  float*  TP  = ws + OFF_T;
  __bf16* WHT = (__bf16*)(ws + OFF_WHT);
  __bf16* KB2 = (__bf16*)(ws + OFF_KB2);  // aliases A (dead until k_ssm)
  __bf16* VB2 = (__bf16*)(ws + OFF_VB2);  // aliases A second half
  __bf16* G   = (__bf16*)(ws + OFF_Q);    // reuse Q region (dead after k_ssm)

  k_tables<<<Hc * Sc / 256, 256, 0, stream>>>(CT, PN);
  k_cast8<<<(BSc * Dc) / (256 * 8), 256, 0, stream>>>(x, XB);
  k_cast8<<<(BSc * Dc) / (256 * 8), 256, 0, stream>>>(k, KB2);
  k_cast8<<<(BSc * Dc) / (256 * 8), 256, 0, stream>>>(v, VB2);
  k_castT<<<dim3(Dc / 32, Dc / 32), 256, 0, stream>>>(wg, WGT);
  k_castT<<<dim3(Dc / 32, Dc / 32), 256, 0, stream>>>(wo, WOT);
  k_whT<<<dim3(4, 4, Hc), 256, 0, stream>>>(Wh, WHT);
  k_projm<<<dim3(BSc / 128, Hc, 3), 512, 0, stream>>>(XB, KB2, VB2, WHT,
                                                      Q, Kp, VB);
  k_vt<<<dim3(Sc / 32, HDc / 32, Bc * Hc), 256, 0, stream>>>(VB, Vt);
  k_vsum<<<dim3(8, Bc * Hc), 256, 0, stream>>>(VB, TP);
  k_vscan<<<Bc * Hc, 128, 0, stream>>>(TP, SUF);
  k_ssm<<<dim3(Sc / 128, Sc / 128, Hc), 512, 0, stream>>>(Q, Kp, CT, PN, A);
  k_avm<<<dim3(Sc / 128, 1, Bc * Hc), 512, 0, stream>>>(A, Vt, SUF, O);
  k_gnorm<<<BSc, 256, 0, stream>>>(O, gg, gb);
  k_mgemm<<<dim3(Dc / 128, BSc / 128), 512, 0, stream>>>(XB, WGT, O, G, nullptr, 0);
  k_mgemm<<<dim3(Dc / 128, BSc / 128), 512, 0, stream>>>(G, WOT, nullptr, nullptr,
                                                         (float*)d_out, 1);
}